// Round 4
// baseline (603.029 us; speedup 1.0000x reference)
//
#include <hip/hip_runtime.h>
#include <hip/hip_bf16.h>
#include <stdint.h>

#define EMBED 1024
#define NTOK 8192

typedef short bf16x8 __attribute__((ext_vector_type(8)));
typedef float f32x4 __attribute__((ext_vector_type(4)));
typedef float f32x16 __attribute__((ext_vector_type(16)));

__device__ inline unsigned short f2bf(float f) {
    union { float f; unsigned u; } c; c.f = f;
    unsigned u = c.u;
    unsigned r = (u + 0x7fffu + ((u >> 16) & 1u)) >> 16;
    return (unsigned short)r;
}

// Cast x -> bf16 (xb, row-major [N][D]) and transposed (xbT, [D][N]) via LDS tile.
__global__ void prep_x(const float* __restrict__ x, unsigned short* __restrict__ xb,
                       unsigned short* __restrict__ xbT) {
    __shared__ unsigned short tile[32][33];
    int bj = blockIdx.x, bi = blockIdx.y;
    int tx = threadIdx.x, ty = threadIdx.y;
#pragma unroll
    for (int r = 0; r < 4; ++r) {
        int row = ty + r * 8;
        size_t gi = (size_t)(bi * 32 + row) * EMBED + bj * 32 + tx;
        unsigned short h = f2bf(x[gi]);
        xb[gi] = h;
        tile[row][tx] = h;
    }
    __syncthreads();
#pragma unroll
    for (int r = 0; r < 4; ++r) {
        int row = ty + r * 8;
        xbT[(size_t)(bj * 32 + row) * NTOK + bi * 32 + tx] = tile[tx][row];
    }
}

// Cast + transpose a 1024x1024 fp32 weight into bf16 wT[n][k] = w[k][n].
__global__ void prep_w(const float* __restrict__ w, unsigned short* __restrict__ wT) {
    __shared__ unsigned short tile[32][33];
    int bj = blockIdx.x, bi = blockIdx.y;   // bi: k tile, bj: n tile
    int tx = threadIdx.x, ty = threadIdx.y;
#pragma unroll
    for (int r = 0; r < 4; ++r) {
        int row = ty + r * 8;
        tile[row][tx] = f2bf(w[(size_t)(bi * 32 + row) * EMBED + bj * 32 + tx]);
    }
    __syncthreads();
#pragma unroll
    for (int r = 0; r < 4; ++r) {
        int row = ty + r * 8;
        wT[(size_t)(bj * 32 + row) * EMBED + bi * 32 + tx] = tile[tx][row];
    }
}

// C[m][n] = sum_k A[m][k] * B[n][k]   (B stored transposed: [n][k])
// Compute: mfma_f32_32x32x16_bf16, each wave owns a 64x64 tile (2x2 of 32x32).
// A/B frag: row = lane&31, k-chunk = lane>>5 (8 contiguous bf16) [m101-pattern].
// C/D: col = lane&31, row = (reg&3) + 8*(reg>>2) + 4*(lane>>5)  [measured m74/m101].
// LDS XOR swizzle: global 16B-chunk c of tile-row r lives at r*64 + ((c^(r&7))*8)
// shorts -> 128B-row-stride 16-way conflict becomes free 2-way [R3: 5e7 -> 5e5].
// MODE 0: store bf16 to C
// MODE 1: store bf16(exp(acc*scale)) to C, atomicAdd row sums into Z
// MODE 2: C (fp32) = acc (beta=0) or += acc (beta=1)
template<int MODE>
__global__ __launch_bounds__(256) void gemm_bt(
    const unsigned short* __restrict__ A, const unsigned short* __restrict__ B,
    void* __restrict__ Cv, int K, int ldA, int ldB, int ldC,
    float scale, float* __restrict__ Z, int beta)
{
    constexpr int SM_SHORTS = (MODE == 2) ? (4 * 32 * 68 * 2) : (2 * 128 * 64);
    __shared__ alignas(16) unsigned short smem[SM_SHORTS];
    unsigned short* As = smem;
    unsigned short* Bs = smem + 128 * 64;
    const int tid  = threadIdx.x;
    const int lane = tid & 63;
    const int wid  = tid >> 6;
    const int wm   = (wid >> 1) << 6;   // wave row offset in tile
    const int wn   = (wid & 1) << 6;    // wave col offset in tile
    const int l31  = lane & 31;
    const int lh   = lane >> 5;
    const size_t mBase = (size_t)blockIdx.y * 128;
    const size_t nBase = (size_t)blockIdx.x * 128;

    f32x16 acc[2][2] = {};

    const int srow = tid >> 3;              // staging row (per it: +32)
    const int scs  = tid & 7;               // staging LDS chunk slot
    for (int k0 = 0; k0 < K; k0 += 64) {
#pragma unroll
        for (int it = 0; it < 4; ++it) {
            int row = srow + it * 32;
            int seg = row * 8 + scs;
            int csw = scs ^ (row & 7);      // global chunk that fills LDS slot scs
            const unsigned short* ga = A + (mBase + row) * (size_t)ldA + k0 + csw * 8;
            __builtin_amdgcn_global_load_lds(
                (const __attribute__((address_space(1))) void*)ga,
                (__attribute__((address_space(3))) void*)(As + seg * 8), 16, 0, 0);
            const unsigned short* gb = B + (nBase + row) * (size_t)ldB + k0 + csw * 8;
            __builtin_amdgcn_global_load_lds(
                (const __attribute__((address_space(1))) void*)gb,
                (__attribute__((address_space(3))) void*)(Bs + seg * 8), 16, 0, 0);
        }
        __syncthreads();
#pragma unroll
        for (int kk = 0; kk < 4; ++kk) {    // K=16 per step
            const int ck = kk * 2 + lh;     // 16B chunk this lane reads
            bf16x8 af[2], bfr[2];
#pragma unroll
            for (int t = 0; t < 2; ++t) {
                int ra = wm + t * 32 + l31;
                int rb = wn + t * 32 + l31;
                af[t]  = *(const bf16x8*)(As + ra * 64 + ((ck ^ (ra & 7)) * 8));
                bfr[t] = *(const bf16x8*)(Bs + rb * 64 + ((ck ^ (rb & 7)) * 8));
            }
#pragma unroll
            for (int mt = 0; mt < 2; ++mt)
#pragma unroll
                for (int nt = 0; nt < 2; ++nt)
                    acc[mt][nt] = __builtin_amdgcn_mfma_f32_32x32x16_bf16(
                        af[mt], bfr[nt], acc[mt][nt], 0, 0, 0);
        }
        __syncthreads();
    }

    // Epilogue: wave-private LDS repack -> coalesced wide stores.
    if constexpr (MODE <= 1) {
        unsigned short* C = (unsigned short*)Cv;
        unsigned short* st = smem + wid * (32 * 72);  // 32 rows x 72-short stride
#pragma unroll
        for (int mt = 0; mt < 2; ++mt) {
            float rs[16];
#pragma unroll
            for (int r = 0; r < 16; ++r) rs[r] = 0.f;
#pragma unroll
            for (int nt = 0; nt < 2; ++nt) {
                f32x16 v = acc[mt][nt];
#pragma unroll
                for (int r = 0; r < 16; ++r) {
                    float val = v[r];
                    if constexpr (MODE == 1) { val = __expf(val * scale); rs[r] += val; }
                    int row = (r & 3) + 8 * (r >> 2) + 4 * lh;
                    st[row * 72 + nt * 32 + l31] = f2bf(val);
                }
            }
            if constexpr (MODE == 1) {
#pragma unroll
                for (int r = 0; r < 16; ++r) {
                    float s = rs[r];
                    s += __shfl_xor(s, 1);
                    s += __shfl_xor(s, 2);
                    s += __shfl_xor(s, 4);
                    s += __shfl_xor(s, 8);
                    s += __shfl_xor(s, 16);   // stays within the 32-lane half
                    if (l31 == 0)
                        atomicAdd(&Z[mBase + wm + mt * 32 + (r & 3) + 8 * (r >> 2) + 4 * lh], s);
                }
            }
#pragma unroll
            for (int pass = 0; pass < 4; ++pass) {
                int row = pass * 8 + (lane >> 3);
                int cc  = (lane & 7) * 8;
                bf16x8 vv = *(const bf16x8*)(st + row * 72 + cc);
                size_t grow = mBase + wm + mt * 32 + row;
                *(bf16x8*)(C + grow * (size_t)ldC + nBase + wn + cc) = vv;
            }
        }
    } else {
        float* C = (float*)Cv;
        float* stf = (float*)smem + wid * (32 * 68);  // 32 rows x 68-float stride
#pragma unroll
        for (int mt = 0; mt < 2; ++mt) {
#pragma unroll
            for (int nt = 0; nt < 2; ++nt) {
                f32x16 v = acc[mt][nt];
#pragma unroll
                for (int r = 0; r < 16; ++r) {
                    int row = (r & 3) + 8 * (r >> 2) + 4 * lh;
                    stf[row * 68 + nt * 32 + l31] = v[r];
                }
            }
#pragma unroll
            for (int pass = 0; pass < 8; ++pass) {
                int row = pass * 4 + (lane >> 4);
                int cc  = (lane & 15) * 4;
                f32x4 vv = *(const f32x4*)(stf + row * 68 + cc);
                float* gp = C + (mBase + wm + mt * 32 + row) * (size_t)ldC + nBase + wn + cc;
                if (beta) {
                    f32x4 old = *(const f32x4*)gp;
                    vv = vv + old;
                }
                *(f32x4*)gp = vv;
            }
        }
    }
}

__global__ void norm_k(float* __restrict__ out, const float* __restrict__ Z) {
    size_t i = (size_t)blockIdx.x * 256 + threadIdx.x;
    out[i] /= Z[i >> 10];
}

extern "C" void kernel_launch(void* const* d_in, const int* in_sizes, int n_in,
                              void* d_out, int out_size, void* d_ws, size_t ws_size,
                              hipStream_t stream) {
    const float* x  = (const float*)d_in[0];
    const float* wq = (const float*)d_in[1];
    const float* wk = (const float*)d_in[2];
    float* out = (float*)d_out;

    char* p = (char*)d_ws;
    unsigned short* xb   = (unsigned short*)p; p += (size_t)NTOK * EMBED * 2;
    unsigned short* xbT  = (unsigned short*)p; p += (size_t)NTOK * EMBED * 2;
    unsigned short* qkb  = (unsigned short*)p; p += (size_t)NTOK * 2 * EMBED * 2;  // [N][2D]: q | k
    unsigned short* wqkT = (unsigned short*)p; p += (size_t)2 * EMBED * EMBED * 2; // [2D][D]
    float* Z = (float*)p; p += (size_t)NTOK * 4;
    unsigned short* P = (unsigned short*)p;

    size_t used  = (size_t)(p - (char*)d_ws);
    size_t avail = ws_size > used ? (ws_size - used) / 2 : 0;  // elems for P
    int NC = NTOK;
    while (NC > 128 && (size_t)NTOK * NC > avail) NC >>= 1;

    hipMemsetAsync(Z, 0, NTOK * sizeof(float), stream);

    prep_x<<<dim3(EMBED / 32, NTOK / 32), dim3(32, 8), 0, stream>>>(x, xb, xbT);
    prep_w<<<dim3(32, 32), dim3(32, 8), 0, stream>>>(wq, wqkT);
    prep_w<<<dim3(32, 32), dim3(32, 8), 0, stream>>>(wk, wqkT + (size_t)EMBED * EMBED);

    // [q | k] = x @ [Wq Wk]  (single N=2048 GEMM, bf16 out)
    gemm_bt<0><<<dim3(2 * EMBED / 128, NTOK / 128), 256, 0, stream>>>(
        xb, wqkT, qkb, EMBED, EMBED, EMBED, 2 * EMBED, 0.f, nullptr, 0);

    const unsigned short* qb = qkb;
    const unsigned short* kb = qkb + EMBED;
    const float scale = 1.0f / 32.0f;
    for (int c0 = 0; c0 < NTOK; c0 += NC) {
        // P = exp(scale * q @ k_chunk^T), Z += row sums
        gemm_bt<1><<<dim3(NC / 128, NTOK / 128), 256, 0, stream>>>(
            qb, kb + (size_t)c0 * 2 * EMBED, P, EMBED, 2 * EMBED, 2 * EMBED, NC, scale, Z, 0);
        // out (+)= P @ x_chunk   (B operand = xbT[d][c0 + j])
        gemm_bt<2><<<dim3(EMBED / 128, NTOK / 128), 256, 0, stream>>>(
            P, xbT + c0, out, NC, NC, NTOK, EMBED, 0.f, nullptr, c0 > 0 ? 1 : 0);
    }

    norm_k<<<(NTOK * EMBED) / 256, 256, 0, stream>>>(out, Z);
}

// Round 5
// 512.503 us; speedup vs baseline: 1.1766x; 1.1766x over previous
//
#include <hip/hip_runtime.h>
#include <hip/hip_bf16.h>
#include <stdint.h>

#define EMBED 1024
#define NTOK 8192

typedef short bf16x8 __attribute__((ext_vector_type(8)));
typedef float f32x4 __attribute__((ext_vector_type(4)));

__device__ inline unsigned short f2bf(float f) {
    union { float f; unsigned u; } c; c.f = f;
    unsigned u = c.u;
    unsigned r = (u + 0x7fffu + ((u >> 16) & 1u)) >> 16;
    return (unsigned short)r;
}

// Cast x -> bf16 (xb, row-major [N][D]) and transposed (xbT, [D][N]) via LDS tile.
__global__ void prep_x(const float* __restrict__ x, unsigned short* __restrict__ xb,
                       unsigned short* __restrict__ xbT) {
    __shared__ unsigned short tile[32][33];
    int bj = blockIdx.x, bi = blockIdx.y;
    int tx = threadIdx.x, ty = threadIdx.y;
#pragma unroll
    for (int r = 0; r < 4; ++r) {
        int row = ty + r * 8;
        size_t gi = (size_t)(bi * 32 + row) * EMBED + bj * 32 + tx;
        unsigned short h = f2bf(x[gi]);
        xb[gi] = h;
        tile[row][tx] = h;
    }
    __syncthreads();
#pragma unroll
    for (int r = 0; r < 4; ++r) {
        int row = ty + r * 8;
        xbT[(size_t)(bj * 32 + row) * NTOK + bi * 32 + tx] = tile[tx][row];
    }
}

// Cast + transpose BOTH 1024x1024 fp32 weights into bf16 wT[n][k] = w[k][n],
// stacked: rows 0..1023 from wq, rows 1024..2047 from wk. blockIdx.z selects.
__global__ void prep_w2(const float* __restrict__ wq, const float* __restrict__ wk,
                        unsigned short* __restrict__ wT) {
    __shared__ unsigned short tile[32][33];
    int bj = blockIdx.x, bi = blockIdx.y;   // bi: k tile, bj: n tile
    int tx = threadIdx.x, ty = threadIdx.y;
    const float* w = blockIdx.z ? wk : wq;
    unsigned short* dst = wT + (size_t)blockIdx.z * EMBED * EMBED;
#pragma unroll
    for (int r = 0; r < 4; ++r) {
        int row = ty + r * 8;
        tile[row][tx] = f2bf(w[(size_t)(bi * 32 + row) * EMBED + bj * 32 + tx]);
    }
    __syncthreads();
#pragma unroll
    for (int r = 0; r < 4; ++r) {
        int row = ty + r * 8;
        dst[(size_t)(bj * 32 + row) * EMBED + bi * 32 + tx] = tile[tx][row];
    }
}

// C[m][n] = sum_k A[m][k] * B[n][k]   (B stored transposed: [n][k])
// 16x16x32 bf16 MFMA, 128x128 tile, 4x4 acc/wave  [R3-proven: 536 us total].
// LDS XOR swizzle: global 16B-chunk c of tile-row r lives at r*64 + ((c^(r&7))*8)
// shorts -> 128B-row-stride 16-way conflict becomes free 2-way [R3: 5e7 -> 5e5].
// Column-band supertile (8 n-tiles/band) for L3/L2 reuse of A/B tiles.
// MODE 0: store bf16 to C
// MODE 1: store bf16(exp(acc*scale)) to C, atomicAdd row sums into Z
// MODE 2: C (fp32) = acc (beta=0) or += acc (beta=1); if Zn, multiply by 1/Zn[row]
template<int MODE>
__global__ __launch_bounds__(256) void gemm_bt(
    const unsigned short* __restrict__ A, const unsigned short* __restrict__ B,
    void* __restrict__ Cv, int K, int ldA, int ldB, int ldC,
    float scale, float* __restrict__ Z, int beta, const float* __restrict__ Zn)
{
    __shared__ alignas(16) unsigned short smem[2 * 128 * 64];   // 32 KB: As|Bs, reused by epilogue
    unsigned short* As = smem;
    unsigned short* Bs = smem + 128 * 64;
    const int tid  = threadIdx.x;
    const int lane = tid & 63;
    const int wid  = tid >> 6;
    const int wm   = (wid >> 1) << 6;   // wave row offset in tile
    const int wn   = (wid & 1) << 6;    // wave col offset in tile
    const int quad = lane >> 4;
    const int l15  = lane & 15;

    // Supertile remap: sweep 8 n-tiles x all m-tiles per band (L3 reuse).
    int bx = blockIdx.x, by = blockIdx.y;
    if ((gridDim.x & 7) == 0) {
        int bid = by * gridDim.x + bx;
        int band_sz = gridDim.y * 8;
        int band = bid / band_sz;
        int rem = bid - band * band_sz;
        by = rem >> 3;
        bx = band * 8 + (rem & 7);
    }
    const size_t mBase = (size_t)by * 128;
    const size_t nBase = (size_t)bx * 128;

    f32x4 acc[4][4] = {};

    const int srow = tid >> 3;              // staging row (per it: +32)
    const int scs  = tid & 7;               // staging LDS chunk slot
    for (int k0 = 0; k0 < K; k0 += 64) {
#pragma unroll
        for (int it = 0; it < 4; ++it) {
            int row = srow + it * 32;
            int seg = row * 8 + scs;
            int csw = scs ^ (row & 7);      // global chunk that fills LDS slot scs
            const unsigned short* ga = A + (mBase + row) * (size_t)ldA + k0 + csw * 8;
            __builtin_amdgcn_global_load_lds(
                (const __attribute__((address_space(1))) void*)ga,
                (__attribute__((address_space(3))) void*)(As + seg * 8), 16, 0, 0);
            const unsigned short* gb = B + (nBase + row) * (size_t)ldB + k0 + csw * 8;
            __builtin_amdgcn_global_load_lds(
                (const __attribute__((address_space(1))) void*)gb,
                (__attribute__((address_space(3))) void*)(Bs + seg * 8), 16, 0, 0);
        }
        __syncthreads();
#pragma unroll
        for (int kk = 0; kk < 64; kk += 32) {
            const int cbase = kk >> 3;      // chunk base: 0 or 4
            bf16x8 af[4], bfr[4];
#pragma unroll
            for (int t = 0; t < 4; ++t) {
                int ra = wm + t * 16 + l15;
                int rb = wn + t * 16 + l15;
                af[t]  = *(const bf16x8*)(As + ra * 64 + (((cbase + quad) ^ (ra & 7)) * 8));
                bfr[t] = *(const bf16x8*)(Bs + rb * 64 + (((cbase + quad) ^ (rb & 7)) * 8));
            }
#pragma unroll
            for (int mt = 0; mt < 4; ++mt)
#pragma unroll
                for (int nt = 0; nt < 4; ++nt)
                    acc[mt][nt] = __builtin_amdgcn_mfma_f32_16x16x32_bf16(
                        af[mt], bfr[nt], acc[mt][nt], 0, 0, 0);
        }
        __syncthreads();
    }

    // Epilogue. C/D layout: col = lane&15, row = quad*4 + reg  [measured m89/m91]
    // Wave-private LDS repack -> coalesced wide stores.
    if constexpr (MODE <= 1) {
        unsigned short* C = (unsigned short*)Cv;
        unsigned short* st = smem + wid * (16 * 72);  // 16 rows x 72-short stride
#pragma unroll
        for (int mt = 0; mt < 4; ++mt) {
            float rs[4] = {0.f, 0.f, 0.f, 0.f};
#pragma unroll
            for (int nt = 0; nt < 4; ++nt) {
                f32x4 v = acc[mt][nt];
#pragma unroll
                for (int r = 0; r < 4; ++r) {
                    float val = v[r];
                    if constexpr (MODE == 1) { val = __expf(val * scale); rs[r] += val; }
                    st[(quad * 4 + r) * 72 + nt * 16 + l15] = f2bf(val);
                }
            }
            if constexpr (MODE == 1) {
#pragma unroll
                for (int r = 0; r < 4; ++r) {
                    float s = rs[r];
                    s += __shfl_xor(s, 1);
                    s += __shfl_xor(s, 2);
                    s += __shfl_xor(s, 4);
                    s += __shfl_xor(s, 8);
                    if (l15 == 0)
                        atomicAdd(&Z[mBase + wm + mt * 16 + quad * 4 + r], s);
                }
            }
#pragma unroll
            for (int pass = 0; pass < 2; ++pass) {
                int row = pass * 8 + (lane >> 3);
                int cc  = (lane & 7) * 8;
                bf16x8 vv = *(const bf16x8*)(st + row * 72 + cc);
                size_t grow = mBase + wm + mt * 16 + row;
                *(bf16x8*)(C + grow * (size_t)ldC + nBase + wn + cc) = vv;
            }
        }
    } else {
        float* C = (float*)Cv;
        float* stf = (float*)smem + wid * (16 * 68);  // 16 rows x 68-float stride
#pragma unroll
        for (int mt = 0; mt < 4; ++mt) {
#pragma unroll
            for (int nt = 0; nt < 4; ++nt) {
                f32x4 v = acc[mt][nt];
#pragma unroll
                for (int r = 0; r < 4; ++r)
                    stf[(quad * 4 + r) * 68 + nt * 16 + l15] = v[r];
            }
#pragma unroll
            for (int pass = 0; pass < 4; ++pass) {
                int row = pass * 4 + (lane >> 4);
                int cc  = (lane & 15) * 4;
                f32x4 vv = *(const f32x4*)(stf + row * 68 + cc);
                size_t grow = mBase + wm + mt * 16 + row;
                float* gp = C + grow * (size_t)ldC + nBase + wn + cc;
                if (beta) {
                    f32x4 old = *(const f32x4*)gp;
                    vv = vv + old;
                }
                if (Zn) {
                    float inv = 1.0f / Zn[grow];
                    vv = vv * inv;
                }
                *(f32x4*)gp = vv;
            }
        }
    }
}

__global__ void norm_k(float* __restrict__ out, const float* __restrict__ Z) {
    size_t i = (size_t)blockIdx.x * 256 + threadIdx.x;
    out[i] /= Z[i >> 10];
}

extern "C" void kernel_launch(void* const* d_in, const int* in_sizes, int n_in,
                              void* d_out, int out_size, void* d_ws, size_t ws_size,
                              hipStream_t stream) {
    const float* x  = (const float*)d_in[0];
    const float* wq = (const float*)d_in[1];
    const float* wk = (const float*)d_in[2];
    float* out = (float*)d_out;

    char* p = (char*)d_ws;
    unsigned short* xb   = (unsigned short*)p; p += (size_t)NTOK * EMBED * 2;
    unsigned short* xbT  = (unsigned short*)p; p += (size_t)NTOK * EMBED * 2;
    unsigned short* qkb  = (unsigned short*)p; p += (size_t)NTOK * 2 * EMBED * 2;  // [N][2D]: q | k
    unsigned short* wqkT = (unsigned short*)p; p += (size_t)2 * EMBED * EMBED * 2; // [2D][D]
    float* Z = (float*)p; p += (size_t)NTOK * 4;
    unsigned short* P = (unsigned short*)p;

    size_t used  = (size_t)(p - (char*)d_ws);
    size_t avail = ws_size > used ? (ws_size - used) / 2 : 0;  // elems for P
    int NC = NTOK;
    while (NC > 128 && (size_t)NTOK * NC > avail) NC >>= 1;
    const bool single = (NC == NTOK);

    hipMemsetAsync(Z, 0, NTOK * sizeof(float), stream);

    prep_x<<<dim3(EMBED / 32, NTOK / 32), dim3(32, 8), 0, stream>>>(x, xb, xbT);
    prep_w2<<<dim3(32, 32, 2), dim3(32, 8), 0, stream>>>(wq, wk, wqkT);

    // [q | k] = x @ [Wq Wk]  (single N=2048 GEMM, bf16 out)
    gemm_bt<0><<<dim3(2 * EMBED / 128, NTOK / 128), 256, 0, stream>>>(
        xb, wqkT, qkb, EMBED, EMBED, EMBED, 2 * EMBED, 0.f, nullptr, 0, nullptr);

    const unsigned short* qb = qkb;
    const unsigned short* kb = qkb + EMBED;
    const float scale = 1.0f / 32.0f;
    for (int c0 = 0; c0 < NTOK; c0 += NC) {
        // P = exp(scale * q @ k_chunk^T), Z += row sums
        gemm_bt<1><<<dim3(NC / 128, NTOK / 128), 256, 0, stream>>>(
            qb, kb + (size_t)c0 * 2 * EMBED, P, EMBED, 2 * EMBED, 2 * EMBED, NC, scale, Z, 0, nullptr);
        // out (+)= P @ x_chunk; single-chunk: also normalize by Z (Z complete)
        gemm_bt<2><<<dim3(EMBED / 128, NTOK / 128), 256, 0, stream>>>(
            P, xbT + c0, out, NC, NC, NTOK, EMBED, 0.f, nullptr, c0 > 0 ? 1 : 0,
            single ? Z : nullptr);
    }

    if (!single)
        norm_k<<<(NTOK * EMBED) / 256, 256, 0, stream>>>(out, Z);
}